// Round 1
// baseline (583.972 us; speedup 1.0000x reference)
//
#include <hip/hip_runtime.h>
#include <hip/hip_bf16.h>

// ---------------------------------------------------------------------------
// MSDA constants (fixed by the reference's setup_inputs)
// ---------------------------------------------------------------------------
#define BS     4
#define NQ     10000
#define NV     13294          // 100*100 + 50*50 + 25*25 + 13*13
#define EMBED  256
#define HEADS  8
#define LEVELS 4
#define POINTS 4
#define DH     32

// ---------------------------------------------------------------------------
// Generic fp32 GEMM: C[M x N] = A[M x 256] @ W[256 x ldw] + bias (+ residual)
// 64x64 tile per 256-thread block, 4x4 accumulator per thread, K staged in LDS.
// grid.x covers M/64 (guarded), grid.y covers N/64.
// ---------------------------------------------------------------------------
__global__ __launch_bounds__(256) void gemm256(
    const float* __restrict__ A, int M,
    const float* __restrict__ W, int ldw,
    const float* __restrict__ bias,
    float* __restrict__ C, int ldc,
    const float* __restrict__ residual)
{
    const int K = 256;
    __shared__ float As[16][64];
    __shared__ float Bs[16][64];

    const int t  = threadIdx.x;
    const int m0 = blockIdx.x * 64;
    const int n0 = blockIdx.y * 64;

    const int tm = (t & 15) * 4;   // m offset within tile (compute)
    const int tn = (t >> 4) * 4;   // n offset within tile (compute)

    // load indices
    const int arow = t >> 2;        // 0..63
    const int ak   = (t & 3) * 4;   // 0,4,8,12
    const int bn   = (t & 15) * 4;  // 0..60
    const int bk   = t >> 4;        // 0..15

    float acc[4][4] = {};

    for (int k0 = 0; k0 < K; k0 += 16) {
        const int row = m0 + arow;
        float4 av = make_float4(0.f, 0.f, 0.f, 0.f);
        if (row < M) av = *(const float4*)&A[row * K + k0 + ak];
        const float4 bv = *(const float4*)&W[(k0 + bk) * ldw + n0 + bn];

        __syncthreads();
        As[ak + 0][arow] = av.x;
        As[ak + 1][arow] = av.y;
        As[ak + 2][arow] = av.z;
        As[ak + 3][arow] = av.w;
        *(float4*)&Bs[bk][bn] = bv;
        __syncthreads();

        #pragma unroll
        for (int k = 0; k < 16; ++k) {
            const float4 a = *(const float4*)&As[k][tm];
            const float4 b = *(const float4*)&Bs[k][tn];
            acc[0][0] += a.x * b.x; acc[0][1] += a.x * b.y; acc[0][2] += a.x * b.z; acc[0][3] += a.x * b.w;
            acc[1][0] += a.y * b.x; acc[1][1] += a.y * b.y; acc[1][2] += a.y * b.z; acc[1][3] += a.y * b.w;
            acc[2][0] += a.z * b.x; acc[2][1] += a.z * b.y; acc[2][2] += a.z * b.z; acc[2][3] += a.z * b.w;
            acc[3][0] += a.w * b.x; acc[3][1] += a.w * b.y; acc[3][2] += a.w * b.z; acc[3][3] += a.w * b.w;
        }
    }

    const float4 bb = *(const float4*)&bias[n0 + tn];
    #pragma unroll
    for (int i = 0; i < 4; ++i) {
        const int row = m0 + tm + i;
        if (row >= M) continue;
        float4 o;
        o.x = acc[i][0] + bb.x;
        o.y = acc[i][1] + bb.y;
        o.z = acc[i][2] + bb.z;
        o.w = acc[i][3] + bb.w;
        if (residual) {
            const float4 r = *(const float4*)&residual[row * ldc + n0 + tn];
            o.x += r.x; o.y += r.y; o.z += r.z; o.w += r.w;
        }
        *(float4*)&C[row * ldc + n0 + tn] = o;
    }
}

// ---------------------------------------------------------------------------
// Fused softmax + bilinear sampling.
// One wave per (b, q): 8 heads x 8 lanes, each lane owns 4 dims (float4).
// v:    (BS, NV, HEADS, DH) fp32
// proj: (BS*NQ, 384)  -- cols [0,256) = offsets (h,l,p,2), [256,384) = logits (h,l*4+p)
// rp:   (BS, NQ, LEVELS, 2)
// out:  (BS*NQ, 256)  -- (h, dh)
// ---------------------------------------------------------------------------
__global__ __launch_bounds__(256) void msda_sample(
    const float* __restrict__ v,
    const float* __restrict__ proj,
    const float* __restrict__ rp,
    float* __restrict__ out)
{
    const int wave = threadIdx.x >> 6;
    const int lane = threadIdx.x & 63;
    const int q = blockIdx.x * 4 + wave;
    const int b = blockIdx.y;
    const int h  = lane >> 3;
    const int d0 = (lane & 7) * 4;

    const int rowq = b * NQ + q;
    const float* prow = proj + rowq * 384;

    // softmax over the 16 (level,point) logits of this head
    float lg[16];
    float mx = -1e30f;
    #pragma unroll
    for (int i = 0; i < 16; ++i) {
        lg[i] = prow[256 + h * 16 + i];
        mx = fmaxf(mx, lg[i]);
    }
    float ssum = 0.f;
    #pragma unroll
    for (int i = 0; i < 16; ++i) {
        lg[i] = __expf(lg[i] - mx);
        ssum += lg[i];
    }
    const float inv = 1.0f / ssum;

    const float* rpq = rp + rowq * (LEVELS * 2);

    const int   Ws[4]     = {100, 50, 25, 13};
    const int   Hs[4]     = {100, 50, 25, 13};
    const int   starts[4] = {0, 10000, 12500, 13125};

    float4 acc = make_float4(0.f, 0.f, 0.f, 0.f);

    #pragma unroll
    for (int l = 0; l < LEVELS; ++l) {
        const int   Wl = Ws[l], Hl = Hs[l], st = starts[l];
        const float fW = (float)Wl, fH = (float)Hl;
        const float rx = rpq[l * 2 + 0];
        const float ry = rpq[l * 2 + 1];
        #pragma unroll
        for (int p = 0; p < POINTS; ++p) {
            const float ox = prow[h * 32 + l * 8 + p * 2 + 0];
            const float oy = prow[h * 32 + l * 8 + p * 2 + 1];
            const float x = fmaf(rx, fW, ox) - 0.5f;
            const float y = fmaf(ry, fH, oy) - 0.5f;
            const float x0f = floorf(x), y0f = floorf(y);
            const float fx = x - x0f, fy = y - y0f;
            const int x0 = (int)x0f, y0 = (int)y0f;
            const float aww = lg[l * 4 + p] * inv;

            #pragma unroll
            for (int c = 0; c < 4; ++c) {
                const int dy = c >> 1, dx = c & 1;
                const int xi = x0 + dx, yi = y0 + dy;
                if (xi >= 0 && xi < Wl && yi >= 0 && yi < Hl) {
                    const float wgt = (dy ? fy : 1.f - fy) * (dx ? fx : 1.f - fx) * aww;
                    const int vi = b * NV + st + yi * Wl + xi;
                    const float4 g = *(const float4*)&v[(vi * HEADS + h) * DH + d0];
                    acc.x += wgt * g.x;
                    acc.y += wgt * g.y;
                    acc.z += wgt * g.z;
                    acc.w += wgt * g.w;
                }
            }
        }
    }

    *(float4*)&out[rowq * 256 + h * 32 + d0] = acc;
}

// ---------------------------------------------------------------------------
// kernel_launch
// inputs (setup_inputs order):
//  0 query (4,10000,256) f32      1 value (4,13294,256) f32
//  2 reference_points (4,10000,4,2) f32   3 spatial_shapes (4,2) i32 (unused; constants)
//  4 Wv (256,256)  5 bv (256)  6 Woff (256,256)  7 boff (256)
//  8 Ww (256,128)  9 bw (128)  10 Wo (256,256)  11 bo (256)
// ---------------------------------------------------------------------------
extern "C" void kernel_launch(void* const* d_in, const int* in_sizes, int n_in,
                              void* d_out, int out_size, void* d_ws, size_t ws_size,
                              hipStream_t stream) {
    const float* query = (const float*)d_in[0];
    const float* value = (const float*)d_in[1];
    const float* rp    = (const float*)d_in[2];
    const float* Wv    = (const float*)d_in[4];
    const float* bv    = (const float*)d_in[5];
    const float* Woff  = (const float*)d_in[6];
    const float* boff  = (const float*)d_in[7];
    const float* Ww    = (const float*)d_in[8];
    const float* bw    = (const float*)d_in[9];
    const float* Wo    = (const float*)d_in[10];
    const float* bo    = (const float*)d_in[11];
    float* out = (float*)d_out;

    char* ws = (char*)d_ws;
    const size_t V_BYTES    = (size_t)BS * NV * EMBED * sizeof(float);   // 54,452,224
    const size_t PROJ_BYTES = (size_t)BS * NQ * 384 * sizeof(float);     // 61,440,000
    float* v    = (float*)ws;
    float* proj = (float*)(ws + V_BYTES);
    float* msda = (float*)(ws + V_BYTES + PROJ_BYTES);

    const int Mv = BS * NV;   // 53176
    const int Mq = BS * NQ;   // 40000

    // 1) v = value @ Wv + bv
    gemm256<<<dim3((Mv + 63) / 64, EMBED / 64), 256, 0, stream>>>(
        value, Mv, Wv, 256, bv, v, 256, nullptr);

    // 2) proj[:, :256] = query @ Woff + boff ; proj[:, 256:384] = query @ Ww + bw
    gemm256<<<dim3(Mq / 64, 256 / 64), 256, 0, stream>>>(
        query, Mq, Woff, 256, boff, proj, 384, nullptr);
    gemm256<<<dim3(Mq / 64, 128 / 64), 256, 0, stream>>>(
        query, Mq, Ww, 128, bw, proj + 256, 384, nullptr);

    // 3) softmax + bilinear sampling
    msda_sample<<<dim3(NQ / 4, BS), 256, 0, stream>>>(v, proj, rp, msda);

    // 4) out = msda @ Wo + bo + query
    gemm256<<<dim3(Mq / 64, 256 / 64), 256, 0, stream>>>(
        msda, Mq, Wo, 256, bo, out, 256, query);
}

// Round 2
// 391.986 us; speedup vs baseline: 1.4898x; 1.4898x over previous
//
#include <hip/hip_runtime.h>
#include <hip/hip_bf16.h>

#define BS     4
#define NQ     10000
#define NV     13294
#define EMBED  256
#define HEADS  8
#define LEVELS 4
#define POINTS 4
#define DH     32

typedef __attribute__((ext_vector_type(8))) short short8;
typedef __attribute__((ext_vector_type(4))) float floatx4;

static __device__ __forceinline__ unsigned short f2b(float f) {
    __hip_bfloat16 h = __float2bfloat16(f);   // RNE
    return *(unsigned short*)&h;
}
static __device__ __forceinline__ float b2f(unsigned short u) {
    return __uint_as_float(((unsigned int)u) << 16);
}

// ---------------------------------------------------------------------------
// Weight prep: transpose+cast to bf16 [N][K], concat (Woff|Ww) and (boff|bw).
// grid = 896 blocks x 256 threads; block n = output row n of [Wvt|Wcatt|Wot].
// ---------------------------------------------------------------------------
__global__ __launch_bounds__(256) void prep_weights(
    const float* __restrict__ Wv,  const float* __restrict__ Woff,
    const float* __restrict__ boff,const float* __restrict__ Ww,
    const float* __restrict__ bw,  const float* __restrict__ Wo,
    unsigned short* __restrict__ Wvt, unsigned short* __restrict__ Wcatt,
    unsigned short* __restrict__ Wot, float* __restrict__ bcat)
{
    const int n = blockIdx.x;
    const int k = threadIdx.x;   // 0..255
    if (n < 256) {
        Wvt[n * 256 + k] = f2b(Wv[k * 256 + n]);
    } else if (n < 512) {
        Wcatt[(n - 256) * 256 + k] = f2b(Woff[k * 256 + (n - 256)]);
    } else if (n < 640) {
        Wcatt[(n - 256) * 256 + k] = f2b(Ww[k * 128 + (n - 512)]);
    } else {
        Wot[(n - 640) * 256 + k] = f2b(Wo[k * 256 + (n - 640)]);
    }
    if (n == 0) {
        for (int j = k; j < 384; j += 256)
            bcat[j] = (j < 256) ? boff[j] : bw[j - 256];
    }
}

// fp32 -> bf16 cast, 4 elems/thread
__global__ __launch_bounds__(256) void cast_bf16(
    const float* __restrict__ in, unsigned short* __restrict__ out, int n4)
{
    const int i = blockIdx.x * 256 + threadIdx.x;
    if (i < n4) {
        const float4 f = ((const float4*)in)[i];
        ushort4 o;
        o.x = f2b(f.x); o.y = f2b(f.y); o.z = f2b(f.z); o.w = f2b(f.w);
        ((ushort4*)out)[i] = o;
    }
}

// ---------------------------------------------------------------------------
// bf16 MFMA GEMM: C[M x N] = A[M x 256] @ Bt^T + bias  (Bt is [N][256] bf16)
// 128x64 tile / 256 threads (4 waves, each 64x32 via 4x2 of 16x16x32 mfma).
// MODE 0: bf16 out; 1: fp32 out; 2: fp32 out + residual.
// ---------------------------------------------------------------------------
#define GBM 128
#define GBN 64
#define GBK 64
#define ASTR 72   // 64 + 8 pad (ushorts)

template<int MODE>
__global__ __launch_bounds__(256) void gemm_mfma(
    const unsigned short* __restrict__ A, int M,
    const unsigned short* __restrict__ Bt,
    const float* __restrict__ bias,
    void* __restrict__ Cv, int ldc,
    const float* __restrict__ residual)
{
    __shared__ __align__(16) unsigned short As[GBM * ASTR];
    __shared__ __align__(16) unsigned short Bsh[GBN * ASTR];

    const int t  = threadIdx.x;
    const int m0 = blockIdx.x * GBM;
    const int n0 = blockIdx.y * GBN;
    const int K  = 256;

    const int wv   = t >> 6;
    const int lane = t & 63;
    const int wm   = (wv & 1) * 64;
    const int wn   = (wv >> 1) * 32;
    const int lr   = lane & 15;
    const int lk   = (lane >> 4) * 8;

    floatx4 acc[4][2] = {};

    // staging indices
    const int ar = t >> 1;           // A row 0..127
    const int ac = (t & 1) * 32;     // A col offset (ushorts), 64B chunk
    const int br = t >> 2;           // B row 0..63
    const int bc = (t & 3) * 16;     // B col offset (ushorts), 32B chunk

    for (int k0 = 0; k0 < K; k0 += GBK) {
        uint4 a0 = {}, a1 = {}, a2 = {}, a3 = {};
        const int arow = m0 + ar;
        if (arow < M) {
            const uint4* src = (const uint4*)(A + (size_t)arow * K + k0 + ac);
            a0 = src[0]; a1 = src[1]; a2 = src[2]; a3 = src[3];
        }
        const uint4* bsrc = (const uint4*)(Bt + (size_t)(n0 + br) * K + k0 + bc);
        const uint4 b0 = bsrc[0], b1 = bsrc[1];

        __syncthreads();
        {
            uint4* dst = (uint4*)&As[ar * ASTR + ac];
            dst[0] = a0; dst[1] = a1; dst[2] = a2; dst[3] = a3;
            uint4* bdst = (uint4*)&Bsh[br * ASTR + bc];
            bdst[0] = b0; bdst[1] = b1;
        }
        __syncthreads();

        #pragma unroll
        for (int kk = 0; kk < GBK; kk += 32) {
            short8 bf0 = *(const short8*)&Bsh[(wn +  0 + lr) * ASTR + kk + lk];
            short8 bf1 = *(const short8*)&Bsh[(wn + 16 + lr) * ASTR + kk + lk];
            #pragma unroll
            for (int mt = 0; mt < 4; ++mt) {
                short8 af = *(const short8*)&As[(wm + mt * 16 + lr) * ASTR + kk + lk];
                acc[mt][0] = __builtin_amdgcn_mfma_f32_16x16x32_bf16(af, bf0, acc[mt][0], 0, 0, 0);
                acc[mt][1] = __builtin_amdgcn_mfma_f32_16x16x32_bf16(af, bf1, acc[mt][1], 0, 0, 0);
            }
        }
    }

    // epilogue: C/D layout col = lane&15, row = (lane>>4)*4 + reg
    const int rbase = m0 + wm + (lane >> 4) * 4;
    #pragma unroll
    for (int nt = 0; nt < 2; ++nt) {
        const int col = n0 + wn + nt * 16 + lr;
        const float bb = bias[col];
        #pragma unroll
        for (int mt = 0; mt < 4; ++mt) {
            #pragma unroll
            for (int r = 0; r < 4; ++r) {
                const int row = rbase + mt * 16 + r;
                if (row < M) {
                    float val = acc[mt][nt][r] + bb;
                    if (MODE == 2) val += residual[(size_t)row * ldc + col];
                    if (MODE == 0)
                        ((unsigned short*)Cv)[(size_t)row * ldc + col] = f2b(val);
                    else
                        ((float*)Cv)[(size_t)row * ldc + col] = val;
                }
            }
        }
    }
}

// ---------------------------------------------------------------------------
// Fused softmax + bilinear sampling. One wave per (b,q); 8 heads x 8 lanes,
// lane owns 4 dims. v is bf16 (BS,NV,HEADS,DH); msda out bf16 (BS*NQ,256).
// ---------------------------------------------------------------------------
__global__ __launch_bounds__(256) void msda_sample(
    const unsigned short* __restrict__ v,
    const float* __restrict__ proj,
    const float* __restrict__ rp,
    unsigned short* __restrict__ out)
{
    const int wave = threadIdx.x >> 6;
    const int lane = threadIdx.x & 63;
    const int q = blockIdx.x * 4 + wave;
    const int b = blockIdx.y;
    const int h  = lane >> 3;
    const int d0 = (lane & 7) * 4;

    const int rowq = b * NQ + q;
    const float* prow = proj + (size_t)rowq * 384;

    float lg[16];
    float mx = -1e30f;
    #pragma unroll
    for (int i = 0; i < 16; ++i) {
        lg[i] = prow[256 + h * 16 + i];
        mx = fmaxf(mx, lg[i]);
    }
    float ssum = 0.f;
    #pragma unroll
    for (int i = 0; i < 16; ++i) {
        lg[i] = __expf(lg[i] - mx);
        ssum += lg[i];
    }
    const float inv = 1.0f / ssum;

    const float* rpq = rp + (size_t)rowq * (LEVELS * 2);

    const int Ws[4]     = {100, 50, 25, 13};
    const int Hs[4]     = {100, 50, 25, 13};
    const int starts[4] = {0, 10000, 12500, 13125};

    float ax = 0.f, ay = 0.f, az = 0.f, aw2 = 0.f;

    #pragma unroll
    for (int l = 0; l < LEVELS; ++l) {
        const int   Wl = Ws[l], Hl = Hs[l], st = starts[l];
        const float fW = (float)Wl, fH = (float)Hl;
        const float rx = rpq[l * 2 + 0];
        const float ry = rpq[l * 2 + 1];
        #pragma unroll
        for (int p = 0; p < POINTS; ++p) {
            const float ox = prow[h * 32 + l * 8 + p * 2 + 0];
            const float oy = prow[h * 32 + l * 8 + p * 2 + 1];
            const float x = fmaf(rx, fW, ox) - 0.5f;
            const float y = fmaf(ry, fH, oy) - 0.5f;
            const float x0f = floorf(x), y0f = floorf(y);
            const float fx = x - x0f, fy = y - y0f;
            const int x0 = (int)x0f, y0 = (int)y0f;
            const float aww = lg[l * 4 + p] * inv;

            #pragma unroll
            for (int c = 0; c < 4; ++c) {
                const int dy = c >> 1, dx = c & 1;
                const int xi = x0 + dx, yi = y0 + dy;
                if (xi >= 0 && xi < Wl && yi >= 0 && yi < Hl) {
                    const float wgt = (dy ? fy : 1.f - fy) * (dx ? fx : 1.f - fx) * aww;
                    const int vi = b * NV + st + yi * Wl + xi;
                    const ushort4 g = *(const ushort4*)&v[((size_t)vi * HEADS + h) * DH + d0];
                    ax = fmaf(wgt, b2f(g.x), ax);
                    ay = fmaf(wgt, b2f(g.y), ay);
                    az = fmaf(wgt, b2f(g.z), az);
                    aw2 = fmaf(wgt, b2f(g.w), aw2);
                }
            }
        }
    }

    ushort4 o;
    o.x = f2b(ax); o.y = f2b(ay); o.z = f2b(az); o.w = f2b(aw2);
    *(ushort4*)&out[(size_t)rowq * 256 + h * 32 + d0] = o;
}

// ---------------------------------------------------------------------------
// kernel_launch
// ---------------------------------------------------------------------------
extern "C" void kernel_launch(void* const* d_in, const int* in_sizes, int n_in,
                              void* d_out, int out_size, void* d_ws, size_t ws_size,
                              hipStream_t stream) {
    const float* query = (const float*)d_in[0];
    const float* value = (const float*)d_in[1];
    const float* rp    = (const float*)d_in[2];
    const float* Wv    = (const float*)d_in[4];
    const float* bv    = (const float*)d_in[5];
    const float* Woff  = (const float*)d_in[6];
    const float* boff  = (const float*)d_in[7];
    const float* Ww    = (const float*)d_in[8];
    const float* bw    = (const float*)d_in[9];
    const float* Wo    = (const float*)d_in[10];
    const float* bo    = (const float*)d_in[11];
    float* out = (float*)d_out;

    const int Mv = BS * NV;   // 53176
    const int Mq = BS * NQ;   // 40000

    // workspace layout (bytes)
    char* ws = (char*)d_ws;
    const size_t SZ_A    = (size_t)Mv * 256 * 2;          // 27,226,112 (value_bf16, later msda_bf16)
    const size_t SZ_V    = (size_t)Mv * 256 * 2;          // 27,226,112
    const size_t SZ_PROJ = (size_t)Mq * 384 * 4;          // 61,440,000
    const size_t SZ_QB   = (size_t)Mq * 256 * 2;          // 20,480,000
    unsigned short* bufA  = (unsigned short*)(ws);                          // value_bf16 then msda_bf16
    unsigned short* v_bf  = (unsigned short*)(ws + SZ_A);
    float*          proj  = (float*)(ws + SZ_A + SZ_V);
    unsigned short* q_bf  = (unsigned short*)(ws + SZ_A + SZ_V + SZ_PROJ);
    char* wp = ws + SZ_A + SZ_V + SZ_PROJ + SZ_QB;
    unsigned short* Wvt   = (unsigned short*)(wp);
    unsigned short* Wcatt = (unsigned short*)(wp + 256 * 256 * 2);
    unsigned short* Wot   = (unsigned short*)(wp + 256 * 256 * 2 + 384 * 256 * 2);
    float*          bcat  = (float*)(wp + 256 * 256 * 2 + 384 * 256 * 2 + 256 * 256 * 2);

    // 0) weight prep + input casts
    prep_weights<<<896, 256, 0, stream>>>(Wv, Woff, boff, Ww, bw, Wo, Wvt, Wcatt, Wot, bcat);
    cast_bf16<<<(Mv * 64 + 255) / 256, 256, 0, stream>>>(value, bufA, Mv * 64);
    cast_bf16<<<(Mq * 64 + 255) / 256, 256, 0, stream>>>(query, q_bf, Mq * 64);

    // 1) v = value @ Wv + bv  (bf16 out)
    gemm_mfma<0><<<dim3((Mv + GBM - 1) / GBM, 256 / GBN), 256, 0, stream>>>(
        bufA, Mv, Wvt, bv, v_bf, 256, nullptr);

    // 2) proj = query @ [Woff|Ww] + [boff|bw]  (fp32 out)
    gemm_mfma<1><<<dim3((Mq + GBM - 1) / GBM, 384 / GBN), 256, 0, stream>>>(
        q_bf, Mq, Wcatt, bcat, proj, 384, nullptr);

    // 3) softmax + sampling -> msda (bf16, reuses bufA)
    msda_sample<<<dim3(NQ / 4, BS), 256, 0, stream>>>(v_bf, proj, rp, bufA);

    // 4) out = msda @ Wo + bo + query
    gemm_mfma<2><<<dim3((Mq + GBM - 1) / GBM, 256 / GBN), 256, 0, stream>>>(
        bufA, Mq, Wot, bo, out, 256, query);
}

// Round 3
// 340.952 us; speedup vs baseline: 1.7128x; 1.1497x over previous
//
#include <hip/hip_runtime.h>
#include <hip/hip_bf16.h>

#define BS     4
#define NQ     10000
#define NV     13294
#define EMBED  256
#define HEADS  8
#define LEVELS 4
#define POINTS 4
#define DH     32

typedef __attribute__((ext_vector_type(8))) short short8;
typedef __attribute__((ext_vector_type(4))) float floatx4;

static __device__ __forceinline__ unsigned short f2b(float f) {
    __hip_bfloat16 h = __float2bfloat16(f);   // RNE
    return *(unsigned short*)&h;
}

// ---------------------------------------------------------------------------
// Weight prep: transpose+cast to bf16 [N][K], concat (Woff|Ww) and (boff|bw).
// Writes coalesced; scattered reads stay in L2 (total weights < 1 MB).
// ---------------------------------------------------------------------------
__global__ __launch_bounds__(256) void prep_weights(
    const float* __restrict__ Wv,  const float* __restrict__ Woff,
    const float* __restrict__ boff,const float* __restrict__ Ww,
    const float* __restrict__ bw,  const float* __restrict__ Wo,
    unsigned short* __restrict__ Wvt, unsigned short* __restrict__ Wcatt,
    unsigned short* __restrict__ Wot, float* __restrict__ bcat)
{
    const int n = blockIdx.x;
    const int k = threadIdx.x;   // 0..255
    if (n < 256) {
        Wvt[n * 256 + k] = f2b(Wv[k * 256 + n]);
    } else if (n < 512) {
        Wcatt[(n - 256) * 256 + k] = f2b(Woff[k * 256 + (n - 256)]);
    } else if (n < 640) {
        Wcatt[(n - 256) * 256 + k] = f2b(Ww[k * 128 + (n - 512)]);
    } else {
        Wot[(n - 640) * 256 + k] = f2b(Wo[k * 256 + (n - 640)]);
    }
    if (n == 0) {
        for (int j = k; j < 384; j += 256)
            bcat[j] = (j < 256) ? boff[j] : bw[j - 256];
    }
}

// fp32 -> bf16 cast, 4 elems/thread
__global__ __launch_bounds__(256) void cast_bf16(
    const float* __restrict__ in, unsigned short* __restrict__ out, int n4)
{
    const int i = blockIdx.x * 256 + threadIdx.x;
    if (i < n4) {
        const float4 f = ((const float4*)in)[i];
        ushort4 o;
        o.x = f2b(f.x); o.y = f2b(f.y); o.z = f2b(f.z); o.w = f2b(f.w);
        ((ushort4*)out)[i] = o;
    }
}

// ---------------------------------------------------------------------------
// bf16 MFMA GEMM: C[M x N] = A[M x 256] @ Bt^T + bias  (Bt is [N][256] bf16)
// 128x128 tile / 256 threads (4 waves, each 64x64 via 4x4 of 16x16x32 mfma).
// MODE 0: bf16 out; 1: fp32 out; 2: fp32 out + residual.
// ---------------------------------------------------------------------------
#define ASTR 72   // 64 + 8 pad (ushorts) -> 2-way-max LDS bank aliasing

template<int MODE>
__global__ __launch_bounds__(256) void gemm_mfma(
    const unsigned short* __restrict__ A, int M,
    const unsigned short* __restrict__ Bt,
    const float* __restrict__ bias,
    void* __restrict__ Cv, int ldc,
    const float* __restrict__ residual)
{
    __shared__ __align__(16) unsigned short As[128 * ASTR];
    __shared__ __align__(16) unsigned short Bsh[128 * ASTR];

    const int t  = threadIdx.x;
    const int m0 = blockIdx.x * 128;
    const int n0 = blockIdx.y * 128;
    const int K  = 256;

    const int wv   = t >> 6;
    const int lane = t & 63;
    const int wm   = (wv & 1) * 64;
    const int wn   = (wv >> 1) * 64;
    const int lr   = lane & 15;
    const int lk   = (lane >> 4) * 8;

    floatx4 acc[4][4] = {};

    // staging: thread stages 32 ushorts (64 B) of A and of B
    const int ar = t >> 1;           // row 0..127
    const int ac = (t & 1) * 32;     // ushort col offset

    for (int k0 = 0; k0 < K; k0 += 64) {
        uint4 a0 = {}, a1 = {}, a2 = {}, a3 = {};
        const int arow = m0 + ar;
        if (arow < M) {
            const uint4* s = (const uint4*)(A + (size_t)arow * K + k0 + ac);
            a0 = s[0]; a1 = s[1]; a2 = s[2]; a3 = s[3];
        }
        const uint4* bs = (const uint4*)(Bt + (size_t)(n0 + ar) * K + k0 + ac);
        const uint4 b0 = bs[0], b1 = bs[1], b2 = bs[2], b3 = bs[3];

        __syncthreads();
        {
            uint4* ad = (uint4*)&As[ar * ASTR + ac];
            ad[0] = a0; ad[1] = a1; ad[2] = a2; ad[3] = a3;
            uint4* bd = (uint4*)&Bsh[ar * ASTR + ac];
            bd[0] = b0; bd[1] = b1; bd[2] = b2; bd[3] = b3;
        }
        __syncthreads();

        #pragma unroll
        for (int kk = 0; kk < 64; kk += 32) {
            short8 bf[4];
            #pragma unroll
            for (int nt = 0; nt < 4; ++nt)
                bf[nt] = *(const short8*)&Bsh[(wn + nt * 16 + lr) * ASTR + kk + lk];
            #pragma unroll
            for (int mt = 0; mt < 4; ++mt) {
                const short8 af = *(const short8*)&As[(wm + mt * 16 + lr) * ASTR + kk + lk];
                #pragma unroll
                for (int nt = 0; nt < 4; ++nt)
                    acc[mt][nt] = __builtin_amdgcn_mfma_f32_16x16x32_bf16(af, bf[nt], acc[mt][nt], 0, 0, 0);
            }
        }
    }

    // epilogue: C/D layout col = lane&15, row = (lane>>4)*4 + reg
    const int rbase = m0 + wm + (lane >> 4) * 4;
    #pragma unroll
    for (int nt = 0; nt < 4; ++nt) {
        const int col = n0 + wn + nt * 16 + lr;
        const float bb = bias[col];
        #pragma unroll
        for (int mt = 0; mt < 4; ++mt) {
            #pragma unroll
            for (int r = 0; r < 4; ++r) {
                const int row = rbase + mt * 16 + r;
                if (row < M) {
                    float val = acc[mt][nt][r] + bb;
                    if (MODE == 2) val += residual[(size_t)row * ldc + col];
                    if (MODE == 0)
                        ((unsigned short*)Cv)[(size_t)row * ldc + col] = f2b(val);
                    else
                        ((float*)Cv)[(size_t)row * ldc + col] = val;
                }
            }
        }
    }
}

// ---------------------------------------------------------------------------
// Fused softmax + bilinear sampling, two-phase.
// One wave per (b,q).
// Phase A: lane = h*8+i computes combos c=2i,2i+1 (c = l*4+p): softmax weight
//   (shuffle-reduced over the 8-lane head group) and the 4 bilinear taps as
//   (byte_offset, weight) pairs -> LDS (head-stride 528 B to spread banks).
// Phase B: lane = h*8+i owns dims d0=(i*4); 64 taps/head: ds_read_b128 gives
//   2 taps; global_load_dwordx2 of bf16x4; shift/and converts; 4 FMAs.
// v: bf16 (BS,NV,HEADS,DH); out: bf16 (BS*NQ,256).
// ---------------------------------------------------------------------------
__global__ __launch_bounds__(256) void msda_sample(
    const unsigned short* __restrict__ v,
    const float* __restrict__ proj,
    const float* __restrict__ rp,
    unsigned short* __restrict__ out)
{
    __shared__ __align__(16) unsigned int taps[4 * 1056];  // 4 waves * 8 heads * 528 B

    const int wave = threadIdx.x >> 6;
    const int lane = threadIdx.x & 63;
    const int q = blockIdx.x * 4 + wave;
    const int b = blockIdx.y;
    const int rowq = b * NQ + q;
    const float* prow = proj + (size_t)rowq * 384;

    // ---- phase A ----
    const int hA = lane >> 3;
    const int li = lane & 7;
    const int c0 = li * 2;

    const float2 lg = *(const float2*)&prow[256 + hA * 16 + c0];
    float mx = fmaxf(lg.x, lg.y);
    mx = fmaxf(mx, __shfl_xor(mx, 1));
    mx = fmaxf(mx, __shfl_xor(mx, 2));
    mx = fmaxf(mx, __shfl_xor(mx, 4));
    const float e0 = __expf(lg.x - mx);
    const float e1 = __expf(lg.y - mx);
    float ssum = e0 + e1;
    ssum += __shfl_xor(ssum, 1);
    ssum += __shfl_xor(ssum, 2);
    ssum += __shfl_xor(ssum, 4);
    const float inv = 1.0f / ssum;

    const int l = c0 >> 2;                     // both combos share the level
    const int Wl = (l == 0) ? 100 : (l == 1) ? 50 : (l == 2) ? 25 : 13;
    const int st = (l == 0) ? 0 : (l == 1) ? 10000 : (l == 2) ? 12500 : 13125;
    const int Hl = Wl;
    const float fW = (float)Wl, fH = (float)Hl;

    const float2 rxy = *(const float2*)&rp[((size_t)rowq * 4 + l) * 2];

    unsigned int* tbase = taps + wave * 1056 + hA * 132;

    #pragma unroll
    for (int cc = 0; cc < 2; ++cc) {
        const int c = c0 + cc;
        const float2 oxy = *(const float2*)&prow[hA * 32 + c * 2];
        const float aww = (cc ? e1 : e0) * inv;
        const float x = fmaf(rxy.x, fW, oxy.x) - 0.5f;
        const float y = fmaf(rxy.y, fH, oxy.y) - 0.5f;
        const float x0f = floorf(x), y0f = floorf(y);
        const float fx = x - x0f, fy = y - y0f;
        const int ix = (int)x0f, iy = (int)y0f;
        const float wxv[2] = {1.f - fx, fx};
        const float wyv[2] = {1.f - fy, fy};

        uint4 ent[2];
        #pragma unroll
        for (int tp = 0; tp < 4; ++tp) {
            const int dy = tp >> 1, dx = tp & 1;
            const int xi = ix + dx, yi = iy + dy;
            const bool ok = (xi >= 0) && (xi < Wl) && (yi >= 0) && (yi < Hl);
            const int cx = min(max(xi, 0), Wl - 1);
            const int cy = min(max(yi, 0), Hl - 1);
            const unsigned int off = (unsigned int)(st + cy * Wl + cx) * 512u + (unsigned int)hA * 64u;
            const float w = ok ? wyv[dy] * wxv[dx] * aww : 0.f;
            ((unsigned int*)&ent[tp >> 1])[(tp & 1) * 2 + 0] = off;
            ((unsigned int*)&ent[tp >> 1])[(tp & 1) * 2 + 1] = __float_as_uint(w);
        }
        *(uint4*)&tbase[(c * 4 + 0) * 2] = ent[0];
        *(uint4*)&tbase[(c * 4 + 2) * 2] = ent[1];
    }

    __syncthreads();

    // ---- phase B ----
    const int h = lane >> 3;
    const unsigned int lane_off = (unsigned int)(lane & 7) * 8u;
    const char* vb = (const char*)v + (size_t)b * NV * 512 + lane_off;
    const uint4* tp4 = (const uint4*)(taps + wave * 1056 + h * 132);

    float a0 = 0.f, a1 = 0.f, a2 = 0.f, a3 = 0.f;
    #pragma unroll 8
    for (int j = 0; j < 32; ++j) {
        const uint4 ee = tp4[j];
        const uint2 g0 = *(const uint2*)(vb + ee.x);
        const uint2 g1 = *(const uint2*)(vb + ee.z);
        const float w0 = __uint_as_float(ee.y);
        const float w1 = __uint_as_float(ee.w);
        a0 = fmaf(w0, __uint_as_float(g0.x << 16), a0);
        a1 = fmaf(w0, __uint_as_float(g0.x & 0xFFFF0000u), a1);
        a2 = fmaf(w0, __uint_as_float(g0.y << 16), a2);
        a3 = fmaf(w0, __uint_as_float(g0.y & 0xFFFF0000u), a3);
        a0 = fmaf(w1, __uint_as_float(g1.x << 16), a0);
        a1 = fmaf(w1, __uint_as_float(g1.x & 0xFFFF0000u), a1);
        a2 = fmaf(w1, __uint_as_float(g1.y << 16), a2);
        a3 = fmaf(w1, __uint_as_float(g1.y & 0xFFFF0000u), a3);
    }

    ushort4 o;
    o.x = f2b(a0); o.y = f2b(a1); o.z = f2b(a2); o.w = f2b(a3);
    *(ushort4*)&out[(size_t)rowq * 256 + h * 32 + (lane & 7) * 4] = o;
}

// ---------------------------------------------------------------------------
// kernel_launch
// ---------------------------------------------------------------------------
extern "C" void kernel_launch(void* const* d_in, const int* in_sizes, int n_in,
                              void* d_out, int out_size, void* d_ws, size_t ws_size,
                              hipStream_t stream) {
    const float* query = (const float*)d_in[0];
    const float* value = (const float*)d_in[1];
    const float* rp    = (const float*)d_in[2];
    const float* Wv    = (const float*)d_in[4];
    const float* bv    = (const float*)d_in[5];
    const float* Woff  = (const float*)d_in[6];
    const float* boff  = (const float*)d_in[7];
    const float* Ww    = (const float*)d_in[8];
    const float* bw    = (const float*)d_in[9];
    const float* Wo    = (const float*)d_in[10];
    const float* bo    = (const float*)d_in[11];
    float* out = (float*)d_out;

    const int Mv = BS * NV;   // 53176
    const int Mq = BS * NQ;   // 40000

    char* ws = (char*)d_ws;
    const size_t SZ_A    = (size_t)Mv * 256 * 2;   // value_bf16, later msda_bf16
    const size_t SZ_V    = (size_t)Mv * 256 * 2;
    const size_t SZ_PROJ = (size_t)Mq * 384 * 4;
    const size_t SZ_QB   = (size_t)Mq * 256 * 2;
    unsigned short* bufA  = (unsigned short*)(ws);
    unsigned short* v_bf  = (unsigned short*)(ws + SZ_A);
    float*          proj  = (float*)(ws + SZ_A + SZ_V);
    unsigned short* q_bf  = (unsigned short*)(ws + SZ_A + SZ_V + SZ_PROJ);
    char* wp = ws + SZ_A + SZ_V + SZ_PROJ + SZ_QB;
    unsigned short* Wvt   = (unsigned short*)(wp);
    unsigned short* Wcatt = (unsigned short*)(wp + 256 * 256 * 2);
    unsigned short* Wot   = (unsigned short*)(wp + 256 * 256 * 2 + 384 * 256 * 2);
    float*          bcat  = (float*)(wp + 256 * 256 * 2 + 384 * 256 * 2 + 256 * 256 * 2);

    prep_weights<<<896, 256, 0, stream>>>(Wv, Woff, boff, Ww, bw, Wo, Wvt, Wcatt, Wot, bcat);
    cast_bf16<<<(Mv * 64 + 255) / 256, 256, 0, stream>>>(value, bufA, Mv * 64);
    cast_bf16<<<(Mq * 64 + 255) / 256, 256, 0, stream>>>(query, q_bf, Mq * 64);

    // 1) v = value @ Wv + bv  (bf16 out)
    gemm_mfma<0><<<dim3((Mv + 127) / 128, 2), 256, 0, stream>>>(
        bufA, Mv, Wvt, bv, v_bf, 256, nullptr);

    // 2) proj = query @ [Woff|Ww] + [boff|bw]  (fp32 out)
    gemm_mfma<1><<<dim3((Mq + 127) / 128, 3), 256, 0, stream>>>(
        q_bf, Mq, Wcatt, bcat, proj, 384, nullptr);

    // 3) softmax + sampling -> msda (bf16, reuses bufA)
    msda_sample<<<dim3(NQ / 4, BS), 256, 0, stream>>>(v_bf, proj, rp, bufA);

    // 4) out = msda @ Wo + bo + query
    gemm_mfma<2><<<dim3((Mq + 127) / 128, 2), 256, 0, stream>>>(
        bufA, Mq, Wot, bo, out, 256, query);
}

// Round 4
// 332.725 us; speedup vs baseline: 1.7551x; 1.0247x over previous
//
#include <hip/hip_runtime.h>
#include <hip/hip_bf16.h>

#define BS     4
#define NQ     10000
#define NV     13294
#define EMBED  256
#define HEADS  8
#define LEVELS 4
#define POINTS 4
#define DH     32

typedef __attribute__((ext_vector_type(8))) short short8;
typedef __attribute__((ext_vector_type(4))) float floatx4;

static __device__ __forceinline__ unsigned short f2b(float f) {
    __hip_bfloat16 h = __float2bfloat16(f);   // RNE
    return *(unsigned short*)&h;
}
static __device__ __forceinline__ float b2f(unsigned short u) {
    return __uint_as_float(((unsigned int)u) << 16);
}
static __device__ __forceinline__ unsigned int pk_bf16(float x, float y) {
    __hip_bfloat162 h = __float22bfloat162_rn(make_float2(x, y));  // v_cvt_pk_bf16_f32
    unsigned int u; __builtin_memcpy(&u, &h, 4); return u;
}

// ---------------------------------------------------------------------------
// Weight prep: transpose+cast to bf16 [N][K], concat (Woff|Ww) and (boff|bw).
// ---------------------------------------------------------------------------
__global__ __launch_bounds__(256) void prep_weights(
    const float* __restrict__ Wv,  const float* __restrict__ Woff,
    const float* __restrict__ boff,const float* __restrict__ Ww,
    const float* __restrict__ bw,  const float* __restrict__ Wo,
    unsigned short* __restrict__ Wvt, unsigned short* __restrict__ Wcatt,
    unsigned short* __restrict__ Wot, float* __restrict__ bcat)
{
    const int n = blockIdx.x;
    const int k = threadIdx.x;   // 0..255
    if (n < 256) {
        Wvt[n * 256 + k] = f2b(Wv[k * 256 + n]);
    } else if (n < 512) {
        Wcatt[(n - 256) * 256 + k] = f2b(Woff[k * 256 + (n - 256)]);
    } else if (n < 640) {
        Wcatt[(n - 256) * 256 + k] = f2b(Ww[k * 128 + (n - 512)]);
    } else {
        Wot[(n - 640) * 256 + k] = f2b(Wo[k * 256 + (n - 640)]);
    }
    if (n == 0) {
        for (int j = k; j < 384; j += 256)
            bcat[j] = (j < 256) ? boff[j] : bw[j - 256];
    }
}

// ---------------------------------------------------------------------------
// bf16 MFMA GEMM body: C[M x N] = A[M x 256] @ Bt^T + bias (Bt = [N][256] bf16)
// 128x128 tile / 256 threads. AF32: A is fp32, converted during staging.
// MODE 0: bf16 out; 2: fp32 out + residual.
// ---------------------------------------------------------------------------
#define ASTR 72   // 64 + 8 pad (ushorts)

template<int MODE, bool AF32>
static __device__ __forceinline__ void gemm_body(
    unsigned short* As, unsigned short* Bsh,
    const void* __restrict__ Aptr, int M,
    const unsigned short* __restrict__ Bt,
    const float* __restrict__ bias,
    void* __restrict__ Cv, int ldc,
    const float* __restrict__ residual,
    int mb, int nb)
{
    const int t  = threadIdx.x;
    const int m0 = mb * 128;
    const int n0 = nb * 128;
    const int K  = 256;

    const int wv   = t >> 6;
    const int lane = t & 63;
    const int wm   = (wv & 1) * 64;
    const int wn   = (wv >> 1) * 64;
    const int lr   = lane & 15;
    const int lk   = (lane >> 4) * 8;

    floatx4 acc[4][4] = {};

    const int ar = t >> 1;           // row 0..127
    const int ac = (t & 1) * 32;     // ushort col offset

    for (int k0 = 0; k0 < K; k0 += 64) {
        uint4 a[4] = {{}, {}, {}, {}};
        const int arow = m0 + ar;
        if (AF32) {
            if (arow < M) {
                const float4* s = (const float4*)((const float*)Aptr + (size_t)arow * K + k0 + ac);
                #pragma unroll
                for (int i = 0; i < 4; ++i) {
                    const float4 f0 = s[2 * i], f1 = s[2 * i + 1];
                    a[i].x = pk_bf16(f0.x, f0.y);
                    a[i].y = pk_bf16(f0.z, f0.w);
                    a[i].z = pk_bf16(f1.x, f1.y);
                    a[i].w = pk_bf16(f1.z, f1.w);
                }
            }
        } else {
            if (arow < M) {
                const uint4* s = (const uint4*)((const unsigned short*)Aptr + (size_t)arow * K + k0 + ac);
                a[0] = s[0]; a[1] = s[1]; a[2] = s[2]; a[3] = s[3];
            }
        }
        const uint4* bs = (const uint4*)(Bt + (size_t)(n0 + ar) * K + k0 + ac);
        const uint4 b0 = bs[0], b1 = bs[1], b2 = bs[2], b3 = bs[3];

        __syncthreads();
        {
            uint4* ad = (uint4*)&As[ar * ASTR + ac];
            ad[0] = a[0]; ad[1] = a[1]; ad[2] = a[2]; ad[3] = a[3];
            uint4* bd = (uint4*)&Bsh[ar * ASTR + ac];
            bd[0] = b0; bd[1] = b1; bd[2] = b2; bd[3] = b3;
        }
        __syncthreads();

        #pragma unroll
        for (int kk = 0; kk < 64; kk += 32) {
            short8 bf[4];
            #pragma unroll
            for (int nt = 0; nt < 4; ++nt)
                bf[nt] = *(const short8*)&Bsh[(wn + nt * 16 + lr) * ASTR + kk + lk];
            #pragma unroll
            for (int mt = 0; mt < 4; ++mt) {
                const short8 af = *(const short8*)&As[(wm + mt * 16 + lr) * ASTR + kk + lk];
                #pragma unroll
                for (int nt = 0; nt < 4; ++nt)
                    acc[mt][nt] = __builtin_amdgcn_mfma_f32_16x16x32_bf16(af, bf[nt], acc[mt][nt], 0, 0, 0);
            }
        }
    }

    // epilogue: C/D layout col = lane&15, row = (lane>>4)*4 + reg
    const int rbase = m0 + wm + (lane >> 4) * 4;
    #pragma unroll
    for (int nt = 0; nt < 4; ++nt) {
        const int col = n0 + wn + nt * 16 + lr;
        const float bb = bias[col];
        #pragma unroll
        for (int mt = 0; mt < 4; ++mt) {
            #pragma unroll
            for (int r = 0; r < 4; ++r) {
                const int row = rbase + mt * 16 + r;
                if (row < M) {
                    float val = acc[mt][nt][r] + bb;
                    if (MODE == 2) val += residual[(size_t)row * ldc + col];
                    if (MODE == 0)
                        ((unsigned short*)Cv)[(size_t)row * ldc + col] = f2b(val);
                    else
                        ((float*)Cv)[(size_t)row * ldc + col] = val;
                }
            }
        }
    }
}

// Fused GEMM-V + GEMM-proj (independent, one dispatch to fill the machine).
// blocks [0, 832): v = value @ Wv + bv          (416 m-blocks x 2 n-blocks)
// blocks [832,1771): proj = query @ Wcat + bcat (313 m-blocks x 3 n-blocks)
__global__ __launch_bounds__(256) void gemm_fused12(
    const float* __restrict__ value, const float* __restrict__ query,
    const unsigned short* __restrict__ Wvt, const unsigned short* __restrict__ Wcatt,
    const float* __restrict__ bv, const float* __restrict__ bcat,
    unsigned short* __restrict__ vout, unsigned short* __restrict__ projout)
{
    __shared__ __align__(16) unsigned short As[128 * ASTR];
    __shared__ __align__(16) unsigned short Bsh[128 * ASTR];
    const unsigned int bid = blockIdx.x;
    if (bid < 832u) {
        gemm_body<0, true>(As, Bsh, value, BS * NV, Wvt, bv, vout, 256, nullptr,
                           (int)(bid >> 1), (int)(bid & 1));
    } else {
        const unsigned int b2 = bid - 832u;
        gemm_body<0, true>(As, Bsh, query, BS * NQ, Wcatt, bcat, projout, 384, nullptr,
                           (int)(b2 / 3u), (int)(b2 % 3u));
    }
}

// out = msda @ Wo + bo + query  (fp32 out)
__global__ __launch_bounds__(256) void gemm_out(
    const unsigned short* __restrict__ msda, const unsigned short* __restrict__ Wot,
    const float* __restrict__ bo, float* __restrict__ out,
    const float* __restrict__ query)
{
    __shared__ __align__(16) unsigned short As[128 * ASTR];
    __shared__ __align__(16) unsigned short Bsh[128 * ASTR];
    gemm_body<2, false>(As, Bsh, msda, BS * NQ, Wot, bo, out, 256, query,
                        (int)blockIdx.x, (int)blockIdx.y);
}

// ---------------------------------------------------------------------------
// Fused softmax + bilinear sampling, two-phase (proj is bf16 now).
// ---------------------------------------------------------------------------
__global__ __launch_bounds__(256) void msda_sample(
    const unsigned short* __restrict__ v,
    const unsigned short* __restrict__ proj,
    const float* __restrict__ rp,
    unsigned short* __restrict__ out)
{
    __shared__ __align__(16) unsigned int taps[4 * 1056];  // 4 waves * 8 heads * 528 B

    const int wave = threadIdx.x >> 6;
    const int lane = threadIdx.x & 63;
    const int q = blockIdx.x * 4 + wave;
    const int b = blockIdx.y;
    const int rowq = b * NQ + q;
    const unsigned short* prow = proj + (size_t)rowq * 384;

    // ---- phase A: lane = h*8+i owns combos c = 2i, 2i+1 ----
    const int hA = lane >> 3;
    const int li = lane & 7;
    const int c0 = li * 2;

    const ushort2 lgu = *(const ushort2*)&prow[256 + hA * 16 + c0];
    const float lgx = b2f(lgu.x), lgy = b2f(lgu.y);
    float mx = fmaxf(lgx, lgy);
    mx = fmaxf(mx, __shfl_xor(mx, 1));
    mx = fmaxf(mx, __shfl_xor(mx, 2));
    mx = fmaxf(mx, __shfl_xor(mx, 4));
    const float e0 = __expf(lgx - mx);
    const float e1 = __expf(lgy - mx);
    float ssum = e0 + e1;
    ssum += __shfl_xor(ssum, 1);
    ssum += __shfl_xor(ssum, 2);
    ssum += __shfl_xor(ssum, 4);
    const float inv = 1.0f / ssum;

    const int l = c0 >> 2;   // both combos share the level
    const int Wl = (l == 0) ? 100 : (l == 1) ? 50 : (l == 2) ? 25 : 13;
    const int st = (l == 0) ? 0 : (l == 1) ? 10000 : (l == 2) ? 12500 : 13125;
    const int Hl = Wl;
    const float fW = (float)Wl, fH = (float)Hl;

    const float2 rxy = *(const float2*)&rp[((size_t)rowq * 4 + l) * 2];

    unsigned int* tbase = taps + wave * 1056 + hA * 132;

    #pragma unroll
    for (int cc = 0; cc < 2; ++cc) {
        const int c = c0 + cc;
        const ushort2 oxyu = *(const ushort2*)&prow[hA * 32 + c * 2];
        const float ox = b2f(oxyu.x), oy = b2f(oxyu.y);
        const float aww = (cc ? e1 : e0) * inv;
        const float x = fmaf(rxy.x, fW, ox) - 0.5f;
        const float y = fmaf(rxy.y, fH, oy) - 0.5f;
        const float x0f = floorf(x), y0f = floorf(y);
        const float fx = x - x0f, fy = y - y0f;
        const int ix = (int)x0f, iy = (int)y0f;
        const float wxv[2] = {1.f - fx, fx};
        const float wyv[2] = {1.f - fy, fy};

        uint4 ent[2];
        #pragma unroll
        for (int tp = 0; tp < 4; ++tp) {
            const int dy = tp >> 1, dx = tp & 1;
            const int xi = ix + dx, yi = iy + dy;
            const bool ok = (xi >= 0) && (xi < Wl) && (yi >= 0) && (yi < Hl);
            const int cx = min(max(xi, 0), Wl - 1);
            const int cy = min(max(yi, 0), Hl - 1);
            const unsigned int off = (unsigned int)(st + cy * Wl + cx) * 512u + (unsigned int)hA * 64u;
            const float w = ok ? wyv[dy] * wxv[dx] * aww : 0.f;
            ((unsigned int*)&ent[tp >> 1])[(tp & 1) * 2 + 0] = off;
            ((unsigned int*)&ent[tp >> 1])[(tp & 1) * 2 + 1] = __float_as_uint(w);
        }
        *(uint4*)&tbase[(c * 4 + 0) * 2] = ent[0];
        *(uint4*)&tbase[(c * 4 + 2) * 2] = ent[1];
    }

    __syncthreads();

    // ---- phase B: lane = h*8+i owns dims i*4..i*4+3; saddr-form gathers ----
    const int h = lane >> 3;
    const unsigned int lane_off = (unsigned int)(lane & 7) * 8u;
    const char* vbase = (const char*)v + (size_t)b * NV * 512;   // wave-uniform
    const uint4* tp4 = (const uint4*)(taps + wave * 1056 + h * 132);

    float a0 = 0.f, a1 = 0.f, a2 = 0.f, a3 = 0.f;
    #pragma unroll 8
    for (int j = 0; j < 32; ++j) {
        const uint4 ee = tp4[j];
        const uint2 g0 = *(const uint2*)(vbase + (ee.x + lane_off));
        const uint2 g1 = *(const uint2*)(vbase + (ee.z + lane_off));
        const float w0 = __uint_as_float(ee.y);
        const float w1 = __uint_as_float(ee.w);
        a0 = fmaf(w0, __uint_as_float(g0.x << 16), a0);
        a1 = fmaf(w0, __uint_as_float(g0.x & 0xFFFF0000u), a1);
        a2 = fmaf(w0, __uint_as_float(g0.y << 16), a2);
        a3 = fmaf(w0, __uint_as_float(g0.y & 0xFFFF0000u), a3);
        a0 = fmaf(w1, __uint_as_float(g1.x << 16), a0);
        a1 = fmaf(w1, __uint_as_float(g1.x & 0xFFFF0000u), a1);
        a2 = fmaf(w1, __uint_as_float(g1.y << 16), a2);
        a3 = fmaf(w1, __uint_as_float(g1.y & 0xFFFF0000u), a3);
    }

    ushort4 o;
    o.x = f2b(a0); o.y = f2b(a1); o.z = f2b(a2); o.w = f2b(a3);
    *(ushort4*)&out[(size_t)rowq * 256 + h * 32 + (lane & 7) * 4] = o;
}

// ---------------------------------------------------------------------------
// kernel_launch
// ---------------------------------------------------------------------------
extern "C" void kernel_launch(void* const* d_in, const int* in_sizes, int n_in,
                              void* d_out, int out_size, void* d_ws, size_t ws_size,
                              hipStream_t stream) {
    const float* query = (const float*)d_in[0];
    const float* value = (const float*)d_in[1];
    const float* rp    = (const float*)d_in[2];
    const float* Wv    = (const float*)d_in[4];
    const float* bv    = (const float*)d_in[5];
    const float* Woff  = (const float*)d_in[6];
    const float* boff  = (const float*)d_in[7];
    const float* Ww    = (const float*)d_in[8];
    const float* bw    = (const float*)d_in[9];
    const float* Wo    = (const float*)d_in[10];
    const float* bo    = (const float*)d_in[11];
    float* out = (float*)d_out;

    const int Mv = BS * NV;   // 53176
    const int Mq = BS * NQ;   // 40000

    char* ws = (char*)d_ws;
    const size_t SZ_MSDA = (size_t)Mq * 256 * 2;   // 20,480,000
    const size_t SZ_V    = (size_t)Mv * 256 * 2;   // 27,226,112
    const size_t SZ_PROJ = (size_t)Mq * 384 * 2;   // 30,720,000
    unsigned short* msda  = (unsigned short*)(ws);
    unsigned short* v_bf  = (unsigned short*)(ws + SZ_MSDA);
    unsigned short* proj  = (unsigned short*)(ws + SZ_MSDA + SZ_V);
    char* wp = ws + SZ_MSDA + SZ_V + SZ_PROJ;
    unsigned short* Wvt   = (unsigned short*)(wp);
    unsigned short* Wcatt = (unsigned short*)(wp + 256 * 256 * 2);
    unsigned short* Wot   = (unsigned short*)(wp + 256 * 256 * 2 + 384 * 256 * 2);
    float*          bcat  = (float*)(wp + 256 * 256 * 2 + 384 * 256 * 2 + 256 * 256 * 2);

    prep_weights<<<896, 256, 0, stream>>>(Wv, Woff, boff, Ww, bw, Wo, Wvt, Wcatt, Wot, bcat);

    // v = value @ Wv + bv (bf16) AND proj = query @ [Woff|Ww] + bias (bf16)
    gemm_fused12<<<832 + 939, 256, 0, stream>>>(
        value, query, Wvt, Wcatt, bv, bcat, v_bf, proj);

    // softmax + sampling -> msda (bf16)
    msda_sample<<<dim3(NQ / 4, BS), 256, 0, stream>>>(v_bf, proj, rp, msda);

    // out = msda @ Wo + bo + query
    gemm_out<<<dim3((Mq + 127) / 128, 2), 256, 0, stream>>>(msda, Wot, bo, out, query);
}